// Round 19
// baseline (568.846 us; speedup 1.0000x reference)
//
#include <hip/hip_runtime.h>
#include <hip/hip_cooperative_groups.h>
#include <cstdint>

namespace cg = cooperative_groups;

#define N_RNA 4000
#define N_DIS 2000
#define NNODE 6016
#define NFDIM 128
#define RDIM 64
#define NE 300000
#define NET (NE + NNODE)
#define NPAIR 500000
#define NTILE (NPAIR / 16)   // 31250
#define MAXD 128
#define FILLB 1196           // ceil(NET/256)
#define PROJB (NNODE / 16)   // 376

typedef float vf4 __attribute__((ext_vector_type(4)));
typedef _Float16 f16x8 __attribute__((ext_vector_type(8)));
typedef _Float16 f16x2 __attribute__((ext_vector_type(2)));

union FragU {
    f16x8 f;
    f16x2 h[4];
    int   u[4];
    uint4 q;
};

__device__ __forceinline__ f16x2 pkrtz(float lo, float hi) {
    auto r = __builtin_amdgcn_cvt_pkrtz(lo, hi);
    return __builtin_bit_cast(f16x2, r);
}
__device__ __forceinline__ vf4 mfma16(const FragU& a, const FragU& b, vf4 c) {
    return __builtin_amdgcn_mfma_f32_16x16x32_f16(a.f, b.f, c, 0, 0, 0);
}
__device__ __forceinline__ unsigned addrelu2(unsigned a, unsigned b) {
    f16x2 x = __builtin_bit_cast(f16x2, a) + __builtin_bit_cast(f16x2, b);
    f16x2 zz = {(_Float16)0.f, (_Float16)0.f};
    x = __builtin_elementwise_max(x, zz);
    return __builtin_bit_cast(unsigned, x);
}

__device__ __forceinline__ FragU trans16(vf4 a, int col, int g) {
    int w0, w1;
    {
        f16x2 p0 = pkrtz(a[0], a[1]);
        f16x2 p1 = pkrtz(a[2], a[3]);
        FragU tmp; tmp.h[0] = p0; tmp.h[1] = p1;
        w0 = tmp.u[0]; w1 = tmp.u[1];
    }
    int addrA = (col + 16 * ((2 * g) & 3)) * 4;
    int addrB = (col + 16 * ((2 * g + 1) & 3)) * 4;
    int j0 = __builtin_amdgcn_ds_bpermute(addrA, w0);
    int j1 = __builtin_amdgcn_ds_bpermute(addrA, w1);
    int j2 = __builtin_amdgcn_ds_bpermute(addrB, w0);
    int j3 = __builtin_amdgcn_ds_bpermute(addrB, w1);
    bool lo2 = g < 2;
    FragU B;
    B.u[0] = lo2 ? j0 : 0;
    B.u[1] = lo2 ? j1 : 0;
    B.u[2] = lo2 ? j2 : 0;
    B.u[3] = lo2 ? j3 : 0;
    return B;
}

// gfrag prep body (one wave; lane l). Permuted out-feature placement for layers 2,3.
__device__ __forceinline__ void prep_frags_lane(int l,
        const float* w2, const float* w3, const float* w4, const float* w5,
        uint4* gfrag) {
    int rho = l & 15, g = l >> 4;
    int fbase = 8 * (rho >> 2) + (rho & 3);
    FragU F;
#pragma unroll
    for (int tt = 0; tt < 2; tt++)
#pragma unroll
        for (int kt = 0; kt < 2; kt++) {
#pragma unroll
            for (int j = 0; j < 4; j++) {
                int k = kt * 32 + g * 8 + 2 * j;
                F.h[j] = pkrtz(w2[k * 32 + fbase + 4 * tt],
                               w2[(k + 1) * 32 + fbase + 4 * tt]);
            }
            gfrag[(tt * 2 + kt) * 64 + l] = F.q;
        }
#pragma unroll
    for (int tt = 0; tt < 2; tt++) {
#pragma unroll
        for (int j = 0; j < 4; j++) {
            int k = g * 8 + 2 * j;
            F.h[j] = pkrtz(w3[k * 32 + fbase + 4 * tt],
                           w3[(k + 1) * 32 + fbase + 4 * tt]);
        }
        gfrag[(4 + tt) * 64 + l] = F.q;
    }
#pragma unroll
    for (int j = 0; j < 4; j++) {
        int k = g * 8 + 2 * j;
        F.h[j] = pkrtz(w4[k * 16 + rho], w4[(k + 1) * 16 + rho]);
    }
    gfrag[6 * 64 + l] = F.q;
#pragma unroll
    for (int j = 0; j < 4; j++) {
        int k = g * 8 + 2 * j;
        if (g < 2 && rho < 8)
            F.h[j] = pkrtz(w5[k * 8 + rho], w5[(k + 1) * 8 + rho]);
        else
            F.u[j] = 0;
    }
    gfrag[7 * 64 + l] = F.q;
}

// Two-phase edge-softmax-aggregate (128 threads). Leaves smf[64] = agg+bias.
#define AGG_BODY_V2(CUR, SLOTS, H, SS, SD, BIAS)                            \
    int deg = (CUR)[node]; if (deg > MAXD) deg = MAXD;                      \
    float sd = (SD)[node];                                                  \
    float myex = 0.f;                                                       \
    if (tid < deg) {                                                        \
        int s = (SLOTS)[node * MAXD + tid];                                 \
        smI[tid] = s;                                                       \
        float v = (SS)[s] + sd;                                             \
        v = v > 0.f ? v : 0.2f * v;                                         \
        myex = __expf(v);                                                   \
        smS[tid] = myex;                                                    \
    }                                                                       \
    float den = myex;                                                       \
    _Pragma("unroll")                                                       \
    for (int off = 1; off < 64; off <<= 1) den += __shfl_xor(den, off);     \
    if (t == 0) smD[wv] = den;                                              \
    __syncthreads();                                                        \
    float fullden = smD[0] + smD[1];                                        \
    int egrp = tid >> 3, q8 = tid & 7;                                      \
    float4 A0 = {0.f, 0.f, 0.f, 0.f}, A1 = {0.f, 0.f, 0.f, 0.f};            \
    _Pragma("unroll 2")                                                     \
    for (int i = egrp; i < deg; i += 16) {                                  \
        float ex = smS[i];                                                  \
        int s = smI[i];                                                     \
        const float4* hp = (const float4*)((H) + (size_t)s * 64 + q8 * 8);  \
        float4 h0 = hp[0], h1 = hp[1];                                      \
        A0.x = fmaf(ex, h0.x, A0.x); A0.y = fmaf(ex, h0.y, A0.y);           \
        A0.z = fmaf(ex, h0.z, A0.z); A0.w = fmaf(ex, h0.w, A0.w);           \
        A1.x = fmaf(ex, h1.x, A1.x); A1.y = fmaf(ex, h1.y, A1.y);           \
        A1.z = fmaf(ex, h1.z, A1.z); A1.w = fmaf(ex, h1.w, A1.w);           \
    }                                                                       \
    _Pragma("unroll")                                                       \
    for (int off = 8; off <= 32; off <<= 1) {                               \
        A0.x += __shfl_xor(A0.x, off); A0.y += __shfl_xor(A0.y, off);       \
        A0.z += __shfl_xor(A0.z, off); A0.w += __shfl_xor(A0.w, off);       \
        A1.x += __shfl_xor(A1.x, off); A1.y += __shfl_xor(A1.y, off);       \
        A1.z += __shfl_xor(A1.z, off); A1.w += __shfl_xor(A1.w, off);       \
    }                                                                       \
    if (t < 8) {                                                            \
        smA[wv][8 * t + 0] = A0.x; smA[wv][8 * t + 1] = A0.y;               \
        smA[wv][8 * t + 2] = A0.z; smA[wv][8 * t + 3] = A0.w;               \
        smA[wv][8 * t + 4] = A1.x; smA[wv][8 * t + 5] = A1.y;               \
        smA[wv][8 * t + 6] = A1.z; smA[wv][8 * t + 7] = A1.w;               \
    }                                                                       \
    __syncthreads();                                                        \
    if (wv == 0) {                                                          \
        float inv = 1.f / fullden;                                          \
        smf[t] = (smA[0][t] + smA[1][t]) * inv + (BIAS)[t];                 \
    }                                                                       \
    __syncthreads();

struct Params {
    const float* x; const int* adj; const int* coo;
    const float* gw0; const float* gas0; const float* gad0; const float* gb0;
    const float* gw1; const float* gas1; const float* gad1; const float* gb1;
    const float* w1; const float* b1; const float* b2; const float* b3;
    const float* b4; const float* b5; const float* w6; const float* b6;
    const float* w2; const float* w3; const float* w4; const float* w5;
    float* hP; float* hP2; _Float16* u1h; _Float16* u2h; uint4* gfrag;
    float* ssrc; float* sdst; float* ssrc2; float* sdst2;
    int* cur; unsigned short* slots; float* out;
};

// MLP chain shared by mega and standalone kernels.
struct MlpState {
    FragU A200, A201, A210, A211, A30, A31, A4f, A5f;
    float bias2[8], bias3[8], bias4[4], bias5[4], w6r[4];
    float b6v;
};
__device__ __forceinline__ void mlp_init(MlpState& S, int lane, const uint4* gfrag,
        const float* b2, const float* b3, const float* b4, const float* b5,
        const float* w6, const float* b6) {
    int g = lane >> 4;
    S.A200.q = gfrag[0 * 64 + lane];
    S.A201.q = gfrag[1 * 64 + lane];
    S.A210.q = gfrag[2 * 64 + lane];
    S.A211.q = gfrag[3 * 64 + lane];
    S.A30.q  = gfrag[4 * 64 + lane];
    S.A31.q  = gfrag[5 * 64 + lane];
    S.A4f.q  = gfrag[6 * 64 + lane];
    S.A5f.q  = gfrag[7 * 64 + lane];
#pragma unroll
    for (int i = 0; i < 8; i++) {
        S.bias2[i] = b2[8 * g + i];
        S.bias3[i] = b3[8 * g + i];
    }
#pragma unroll
    for (int r = 0; r < 4; r++) {
        S.bias4[r] = b4[g * 4 + r];
        S.bias5[r] = (g < 2) ? b5[g * 4 + r] : 0.f;
        S.w6r[r]   = (g < 2) ? w6[g * 4 + r] : 0.f;
    }
    S.b6v = b6[0];
}
__device__ __forceinline__ float mlp_chain(const MlpState& S, int col, int g,
        uint4 r0, uint4 r1, uint4 d0, uint4 d1) {
    const vf4 z = {0.f, 0.f, 0.f, 0.f};
    FragU B0, B1;
    B0.u[0] = addrelu2(r0.x, d0.x);
    B0.u[1] = addrelu2(r0.y, d0.y);
    B0.u[2] = addrelu2(r0.z, d0.z);
    B0.u[3] = addrelu2(r0.w, d0.w);
    B1.u[0] = addrelu2(r1.x, d1.x);
    B1.u[1] = addrelu2(r1.y, d1.y);
    B1.u[2] = addrelu2(r1.z, d1.z);
    B1.u[3] = addrelu2(r1.w, d1.w);
    vf4 acc0 = mfma16(S.A200, B0, z);
    acc0 = mfma16(S.A201, B1, acc0);
    vf4 acc1 = mfma16(S.A210, B0, z);
    acc1 = mfma16(S.A211, B1, acc1);
#pragma unroll
    for (int r = 0; r < 4; r++) {
        acc0[r] = fmaxf(acc0[r] + S.bias2[r], 0.f);
        acc1[r] = fmaxf(acc1[r] + S.bias2[4 + r], 0.f);
    }
    FragU Bx;
    Bx.h[0] = pkrtz(acc0[0], acc0[1]);
    Bx.h[1] = pkrtz(acc0[2], acc0[3]);
    Bx.h[2] = pkrtz(acc1[0], acc1[1]);
    Bx.h[3] = pkrtz(acc1[2], acc1[3]);
    acc0 = mfma16(S.A30, Bx, z);
    acc1 = mfma16(S.A31, Bx, z);
#pragma unroll
    for (int r = 0; r < 4; r++) {
        acc0[r] = fmaxf(acc0[r] + S.bias3[r], 0.f);
        acc1[r] = fmaxf(acc1[r] + S.bias3[4 + r], 0.f);
    }
    Bx.h[0] = pkrtz(acc0[0], acc0[1]);
    Bx.h[1] = pkrtz(acc0[2], acc0[3]);
    Bx.h[2] = pkrtz(acc1[0], acc1[1]);
    Bx.h[3] = pkrtz(acc1[2], acc1[3]);
    vf4 a4 = mfma16(S.A4f, Bx, z);
#pragma unroll
    for (int r = 0; r < 4; r++) a4[r] = fmaxf(a4[r] + S.bias4[r], 0.f);
    Bx = trans16(a4, col, g);
    vf4 a5 = mfma16(S.A5f, Bx, z);
    float part = 0.f;
#pragma unroll
    for (int r = 0; r < 4; r++)
        part = fmaf(fmaxf(a5[r] + S.bias5[r], 0.f), S.w6r[r], part);
    part += __shfl_xor(part, 16);
    return 1.f / (1.f + __expf(-(part + S.b6v)));
}
// load-ahead-1 MLP loop (works for any wave count)
__device__ __forceinline__ void mlp_loop(const MlpState& S, int wid, int nwaves,
        int lane, const _Float16* u1h, const _Float16* u2h, const int* coo,
        float* out) {
    const int col = lane & 15, g = lane >> 4;
    int tile = wid;
    uint4 r0, r1, d0, d1;
    if (tile < NTILE) {
        int pp = tile * 16 + col;
        int2 rd = ((const int2*)coo)[pp];
        const uint4* pr = (const uint4*)(u1h + (size_t)rd.x * 64);
        const uint4* pd = (const uint4*)(u2h + (size_t)rd.y * 64);
        r0 = pr[g]; r1 = pr[4 + g]; d0 = pd[g]; d1 = pd[4 + g];
    }
    while (tile < NTILE) {
        int next = tile + nwaves;
        uint4 nr0, nr1, nd0, nd1;
        if (next < NTILE) {
            int pp = next * 16 + col;
            int2 rd = ((const int2*)coo)[pp];
            const uint4* pr = (const uint4*)(u1h + (size_t)rd.x * 64);
            const uint4* pd = (const uint4*)(u2h + (size_t)rd.y * 64);
            nr0 = pr[g]; nr1 = pr[4 + g]; nd0 = pd[g]; nd1 = pd[4 + g];
        }
        float sig = mlp_chain(S, col, g, r0, r1, d0, d1);
        if (g == 0) out[tile * 16 + col] = sig;
        tile = next;
        r0 = nr0; r1 = nr1; d0 = nd0; d1 = nd1;
    }
}

// ================= cooperative mega-kernel (grid-stride everything) =================
__global__ __launch_bounds__(128) void mega_kernel(Params p) {
    __shared__ float xr[8][NFDIM];
    __shared__ float smS[MAXD];
    __shared__ int   smI[MAXD];
    __shared__ float smA[2][64];
    __shared__ float smD[2];
    __shared__ float smf[64];
    __shared__ float smP[64];

    const int bid = blockIdx.x;
    const int tid = threadIdx.x;
    const int wv  = tid >> 6;
    const int t   = tid & 63;
    const int nblk = gridDim.x;
    const int nthr = nblk * 128;
    const int gid = bid * 128 + tid;
    cg::grid_group G = cg::this_grid();

    // Phase A: zero counters + gfrag prep
    for (int i = gid; i < NNODE; i += nthr) p.cur[i] = 0;
    if (bid == 0 && tid < 64) prep_frags_lane(tid, p.w2, p.w3, p.w4, p.w5, p.gfrag);
    G.sync();

    // Phase B: slot fill (grid-stride)
    for (int k = gid; k < NET; k += nthr) {
        int src, dst;
        if (k < NE) { src = p.adj[k]; dst = p.adj[NE + k]; }
        else        { src = k - NE; dst = k - NE; }
        int pos = atomicAdd(&p.cur[dst], 1);
        if (pos < MAXD) p.slots[dst * MAXD + pos] = (unsigned short)src;
    }
    // Phase C: proj1, per-wave (no block barrier: each wave uses only its xr half)
    for (int w = bid * 2 + wv; w < NNODE / 4; w += nblk * 2) {
        int nb = w * 4;
        for (int idx = t; idx < 4 * NFDIM; idx += 64)
            xr[wv * 4 + idx / NFDIM][idx % NFDIM] = p.x[(size_t)nb * NFDIM + idx];
        float a0 = 0.f, a1 = 0.f, a2 = 0.f, a3 = 0.f;
#pragma unroll 8
        for (int k = 0; k < NFDIM; k++) {
            float wvv = p.gw0[k * RDIM + t];
            a0 = fmaf(xr[wv * 4 + 0][k], wvv, a0);
            a1 = fmaf(xr[wv * 4 + 1][k], wvv, a1);
            a2 = fmaf(xr[wv * 4 + 2][k], wvv, a2);
            a3 = fmaf(xr[wv * 4 + 3][k], wvv, a3);
        }
        p.hP[(size_t)(nb + 0) * RDIM + t] = a0;
        p.hP[(size_t)(nb + 1) * RDIM + t] = a1;
        p.hP[(size_t)(nb + 2) * RDIM + t] = a2;
        p.hP[(size_t)(nb + 3) * RDIM + t] = a3;
        float asv = p.gas0[t], adv = p.gad0[t];
        float acc[4] = {a0, a1, a2, a3};
#pragma unroll
        for (int i = 0; i < 4; i++) {
            float vs = acc[i] * asv;
            float vd = acc[i] * adv;
#pragma unroll
            for (int off = 32; off; off >>= 1) {
                vs += __shfl_down(vs, off);
                vd += __shfl_down(vd, off);
            }
            if (t == 0) { p.ssrc[nb + i] = vs; p.sdst[nb + i] = vd; }
        }
    }
    G.sync();

    // Phase D: agg1 + proj2 (node = bid-strided; barrier-uniform per block)
    for (int node = bid; node < NNODE; node += nblk) {
        AGG_BODY_V2(p.cur, p.slots, p.hP, p.ssrc, p.sdst, p.gb0)
        float part = 0.f;
        int k0 = wv * 32;
#pragma unroll 8
        for (int k = 0; k < 32; k++)
            part = fmaf(smf[k0 + k], p.gw1[(k0 + k) * 64 + t], part);
        if (wv == 1) smP[t] = part;
        __syncthreads();
        if (wv == 0) {
            float hv = part + smP[t];
            p.hP2[(size_t)node * 64 + t] = hv;
            float vs = hv * p.gas1[t];
            float vd = hv * p.gad1[t];
#pragma unroll
            for (int off = 32; off; off >>= 1) {
                vs += __shfl_down(vs, off);
                vd += __shfl_down(vd, off);
            }
            if (t == 0) { p.ssrc2[node] = vs; p.sdst2[node] = vd; }
        }
        __syncthreads();
    }
    G.sync();

    // Phase E: agg2 + u-precompute
    for (int node = bid; node < N_RNA + N_DIS; node += nblk) {
        AGG_BODY_V2(p.cur, p.slots, p.hP2, p.ssrc2, p.sdst2, p.gb1)
        bool rna = node < N_RNA;
        const float* w = rna ? p.w1 : (p.w1 + 64 * 64);
        float part = (wv == 0 && rna) ? p.b1[t] : 0.f;
        int k0 = wv * 32;
#pragma unroll 8
        for (int k = 0; k < 32; k++)
            part = fmaf(smf[k0 + k], w[(k0 + k) * 64 + t], part);
        if (wv == 1) smP[t] = part;
        __syncthreads();
        if (wv == 0) {
            float uk = part + smP[t];
            _Float16* dst = rna ? (p.u1h + (size_t)node * 64)
                                : (p.u2h + (size_t)(node - N_RNA) * 64);
            dst[t] = (_Float16)uk;
        }
        __syncthreads();
    }
    G.sync();

    // Phase F: pairwise MLP
    {
        MlpState S;
        mlp_init(S, t, p.gfrag, p.b2, p.b3, p.b4, p.b5, p.w6, p.b6);
        mlp_loop(S, bid * 2 + wv, nblk * 2, t, p.u1h, p.u2h, p.coo, p.out);
    }
}

// ================= fallback 5-kernel pipeline (R15-proven, ushort slots) =============
__global__ void setup_kernel(int* __restrict__ cur,
                             const float* __restrict__ w2, const float* __restrict__ w3,
                             const float* __restrict__ w4, const float* __restrict__ w5,
                             uint4* __restrict__ gfrag) {
    int i = blockIdx.x * blockDim.x + threadIdx.x;
    if (i < NNODE) cur[i] = 0;
    if (blockIdx.x == 0 && threadIdx.x < 64)
        prep_frags_lane(threadIdx.x, w2, w3, w4, w5, gfrag);
}

__global__ __launch_bounds__(256) void fill_proj_kernel(
    const int* __restrict__ adj, int* __restrict__ cur, unsigned short* __restrict__ slots,
    const float* __restrict__ x, const float* __restrict__ W,
    const float* __restrict__ a_s, const float* __restrict__ a_d,
    float* __restrict__ h, float* __restrict__ ssrc, float* __restrict__ sdst) {
    int b = blockIdx.x;
    if (b < FILLB) {
        int k = b * 256 + threadIdx.x;
        if (k >= NET) return;
        int src, dst;
        if (k < NE) { src = adj[k]; dst = adj[NE + k]; }
        else        { src = k - NE; dst = k - NE; }
        int pos = atomicAdd(&cur[dst], 1);
        if (pos < MAXD) slots[dst * MAXD + pos] = (unsigned short)src;
        return;
    }
    __shared__ float xr[16][NFDIM];
    int pb = b - FILLB;
    int wv = threadIdx.x >> 6, t = threadIdx.x & 63;
    int nb = pb * 16 + wv * 4;
    for (int idx = t; idx < 4 * NFDIM; idx += 64)
        xr[wv * 4 + idx / NFDIM][idx % NFDIM] = x[(size_t)nb * NFDIM + idx];
    __syncthreads();
    float a0 = 0.f, a1 = 0.f, a2 = 0.f, a3 = 0.f;
#pragma unroll 8
    for (int k = 0; k < NFDIM; k++) {
        float wvv = W[k * RDIM + t];
        a0 = fmaf(xr[wv * 4 + 0][k], wvv, a0);
        a1 = fmaf(xr[wv * 4 + 1][k], wvv, a1);
        a2 = fmaf(xr[wv * 4 + 2][k], wvv, a2);
        a3 = fmaf(xr[wv * 4 + 3][k], wvv, a3);
    }
    h[(size_t)(nb + 0) * RDIM + t] = a0;
    h[(size_t)(nb + 1) * RDIM + t] = a1;
    h[(size_t)(nb + 2) * RDIM + t] = a2;
    h[(size_t)(nb + 3) * RDIM + t] = a3;
    float asv = a_s[t], adv = a_d[t];
    float acc[4] = {a0, a1, a2, a3};
#pragma unroll
    for (int i = 0; i < 4; i++) {
        float vs = acc[i] * asv;
        float vd = acc[i] * adv;
#pragma unroll
        for (int off = 32; off; off >>= 1) {
            vs += __shfl_down(vs, off);
            vd += __shfl_down(vd, off);
        }
        if (t == 0) { ssrc[nb + i] = vs; sdst[nb + i] = vd; }
    }
}

__global__ __launch_bounds__(128) void agg_proj_kernel(
    const float* __restrict__ h, const float* __restrict__ ssrc, const float* __restrict__ sdst,
    const int* __restrict__ cur, const unsigned short* __restrict__ slots,
    const float* __restrict__ bias, const float* __restrict__ W,
    const float* __restrict__ a_s, const float* __restrict__ a_d,
    float* __restrict__ h2, float* __restrict__ ssrc2, float* __restrict__ sdst2) {
    __shared__ float smS[MAXD];
    __shared__ int   smI[MAXD];
    __shared__ float smA[2][64];
    __shared__ float smD[2];
    __shared__ float smf[64];
    __shared__ float smP[64];
    int node = blockIdx.x;
    int tid = threadIdx.x;
    int wv = tid >> 6, t = tid & 63;
    AGG_BODY_V2(cur, slots, h, ssrc, sdst, bias)
    float part = 0.f;
    int k0 = wv * 32;
#pragma unroll 8
    for (int k = 0; k < 32; k++) part = fmaf(smf[k0 + k], W[(k0 + k) * 64 + t], part);
    if (wv == 1) smP[t] = part;
    __syncthreads();
    if (wv == 0) {
        float hv = part + smP[t];
        h2[(size_t)node * 64 + t] = hv;
        float vs = hv * a_s[t];
        float vd = hv * a_d[t];
#pragma unroll
        for (int off = 32; off; off >>= 1) {
            vs += __shfl_down(vs, off);
            vd += __shfl_down(vd, off);
        }
        if (t == 0) { ssrc2[node] = vs; sdst2[node] = vd; }
    }
}

__global__ __launch_bounds__(128) void agg_pre_kernel(
    const float* __restrict__ h, const float* __restrict__ ssrc, const float* __restrict__ sdst,
    const int* __restrict__ cur, const unsigned short* __restrict__ slots,
    const float* __restrict__ bias,
    const float* __restrict__ w1, const float* __restrict__ b1,
    _Float16* __restrict__ u1h, _Float16* __restrict__ u2h) {
    __shared__ float smS[MAXD];
    __shared__ int   smI[MAXD];
    __shared__ float smA[2][64];
    __shared__ float smD[2];
    __shared__ float smf[64];
    __shared__ float smP[64];
    int node = blockIdx.x;
    int tid = threadIdx.x;
    int wv = tid >> 6, t = tid & 63;
    AGG_BODY_V2(cur, slots, h, ssrc, sdst, bias)
    bool rna = node < N_RNA;
    const float* w = rna ? w1 : (w1 + 64 * 64);
    float part = (wv == 0 && rna) ? b1[t] : 0.f;
    int k0 = wv * 32;
#pragma unroll 8
    for (int k = 0; k < 32; k++) part = fmaf(smf[k0 + k], w[(k0 + k) * 64 + t], part);
    if (wv == 1) smP[t] = part;
    __syncthreads();
    if (wv == 0) {
        float uk = part + smP[t];
        _Float16* dst = rna ? (u1h + (size_t)node * 64) : (u2h + (size_t)(node - N_RNA) * 64);
        dst[t] = (_Float16)uk;
    }
}

__global__ __launch_bounds__(256) void mlp_mfma_kernel(
    const _Float16* __restrict__ u1h, const _Float16* __restrict__ u2h,
    const int* __restrict__ coo, const uint4* __restrict__ gfrag,
    const float* __restrict__ b2, const float* __restrict__ b3,
    const float* __restrict__ b4, const float* __restrict__ b5,
    const float* __restrict__ w6, const float* __restrict__ b6,
    float* __restrict__ out) {
    int tid = threadIdx.x;
    const int lane = tid & 63;
    MlpState S;
    mlp_init(S, lane, gfrag, b2, b3, b4, b5, w6, b6);
    mlp_loop(S, blockIdx.x * 4 + (tid >> 6), gridDim.x * 4, lane, u1h, u2h, coo, out);
}

// ---------------- launch ----------------
extern "C" void kernel_launch(void* const* d_in, const int* in_sizes, int n_in,
                              void* d_out, int out_size, void* d_ws, size_t ws_size,
                              hipStream_t stream) {
    char* ws = (char*)d_ws;
    size_t o = 0;
    auto take = [&](size_t bytes) -> void* {
        void* ptr = ws + o;
        o = (o + bytes + 255) & ~(size_t)255;
        return ptr;
    };
    float*          hP    = (float*)take((size_t)NNODE * RDIM * 4);
    float*          hP2   = (float*)take((size_t)NNODE * RDIM * 4);
    _Float16*       u1h   = (_Float16*)take((size_t)N_RNA * 64 * 2);
    _Float16*       u2h   = (_Float16*)take((size_t)N_DIS * 64 * 2);
    uint4*          gfrag = (uint4*)take((size_t)8 * 64 * 16);
    float*          ssrc  = (float*)take((size_t)NNODE * 4);
    float*          sdst  = (float*)take((size_t)NNODE * 4);
    float*          ssrc2 = (float*)take((size_t)NNODE * 4);
    float*          sdst2 = (float*)take((size_t)NNODE * 4);
    int*            cur   = (int*)take((size_t)NNODE * 4);
    unsigned short* slots = (unsigned short*)take((size_t)NNODE * MAXD * 2);

    Params p;
    p.x    = (const float*)d_in[0];
    p.adj  = (const int*)d_in[1];
    p.coo  = (const int*)d_in[2];
    p.gw0  = (const float*)d_in[3];
    p.gas0 = (const float*)d_in[4];
    p.gad0 = (const float*)d_in[5];
    p.gb0  = (const float*)d_in[6];
    p.gw1  = (const float*)d_in[7];
    p.gas1 = (const float*)d_in[8];
    p.gad1 = (const float*)d_in[9];
    p.gb1  = (const float*)d_in[10];
    p.w1   = (const float*)d_in[11];
    p.b1   = (const float*)d_in[12];
    p.w2   = (const float*)d_in[13];
    p.b2   = (const float*)d_in[14];
    p.w3   = (const float*)d_in[15];
    p.b3   = (const float*)d_in[16];
    p.w4   = (const float*)d_in[17];
    p.b4   = (const float*)d_in[18];
    p.w5   = (const float*)d_in[19];
    p.b5   = (const float*)d_in[20];
    p.w6   = (const float*)d_in[21];
    p.b6   = (const float*)d_in[22];
    p.hP = hP; p.hP2 = hP2; p.u1h = u1h; p.u2h = u2h; p.gfrag = gfrag;
    p.ssrc = ssrc; p.sdst = sdst; p.ssrc2 = ssrc2; p.sdst2 = sdst2;
    p.cur = cur; p.slots = slots; p.out = (float*)d_out;

    // occupancy-clamped cooperative launch
    int maxB = 0;
    hipError_t qe = hipOccupancyMaxActiveBlocksPerMultiprocessor(&maxB, mega_kernel, 128, 0);
    int grid = 1792;
    if (qe == hipSuccess && maxB > 0) {
        int cap = maxB * 256;
        if (grid > cap) grid = cap;
    } else {
        grid = 1024;  // conservative
    }
    void* args[] = { &p };
    hipError_t err = hipLaunchCooperativeKernel((const void*)mega_kernel,
                                                dim3(grid), dim3(128), args, 0, stream);
    if (err != hipSuccess) {
        // fallback: proven 5-kernel pipeline
        setup_kernel<<<(NNODE + 255) / 256, 256, 0, stream>>>(
            cur, p.w2, p.w3, p.w4, p.w5, gfrag);
        fill_proj_kernel<<<FILLB + PROJB, 256, 0, stream>>>(
            p.adj, cur, slots, p.x, p.gw0, p.gas0, p.gad0, hP, ssrc, sdst);
        agg_proj_kernel<<<NNODE, 128, 0, stream>>>(
            hP, ssrc, sdst, cur, slots, p.gb0, p.gw1, p.gas1, p.gad1, hP2, ssrc2, sdst2);
        agg_pre_kernel<<<N_RNA + N_DIS, 128, 0, stream>>>(
            hP2, ssrc2, sdst2, cur, slots, p.gb1, p.w1, p.b1, u1h, u2h);
        mlp_mfma_kernel<<<2048, 256, 0, stream>>>(
            u1h, u2h, p.coo, gfrag, p.b2, p.b3, p.b4, p.b5, p.w6, p.b6, (float*)d_out);
    }
}

// Round 20
// 79.065 us; speedup vs baseline: 7.1947x; 7.1947x over previous
//
#include <hip/hip_runtime.h>
#include <cstdint>

#define N_RNA 4000
#define N_DIS 2000
#define NNODE 6016
#define NFDIM 128
#define RDIM 64
#define NE 300000
#define NET (NE + NNODE)
#define NPAIR 500000
#define NTILE (NPAIR / 16)   // 31250
#define MAXD 128
#define FILLB 1196           // ceil(NET/256)
#define PROJB (NNODE / 16)   // 376

typedef float vf4 __attribute__((ext_vector_type(4)));
typedef _Float16 f16x8 __attribute__((ext_vector_type(8)));
typedef _Float16 f16x2 __attribute__((ext_vector_type(2)));

union FragU {
    f16x8 f;
    f16x2 h[4];
    int   u[4];
    uint4 q;
};

__device__ __forceinline__ f16x2 pkrtz(float lo, float hi) {
    auto r = __builtin_amdgcn_cvt_pkrtz(lo, hi);
    return __builtin_bit_cast(f16x2, r);
}
__device__ __forceinline__ vf4 mfma16(const FragU& a, const FragU& b, vf4 c) {
    return __builtin_amdgcn_mfma_f32_16x16x32_f16(a.f, b.f, c, 0, 0, 0);
}
__device__ __forceinline__ unsigned addrelu2(unsigned a, unsigned b) {
    f16x2 x = __builtin_bit_cast(f16x2, a) + __builtin_bit_cast(f16x2, b);
    f16x2 zz = {(_Float16)0.f, (_Float16)0.f};
    x = __builtin_elementwise_max(x, zz);
    return __builtin_bit_cast(unsigned, x);
}

__device__ __forceinline__ FragU trans16(vf4 a, int col, int g) {
    int w0, w1;
    {
        f16x2 p0 = pkrtz(a[0], a[1]);
        f16x2 p1 = pkrtz(a[2], a[3]);
        FragU tmp; tmp.h[0] = p0; tmp.h[1] = p1;
        w0 = tmp.u[0]; w1 = tmp.u[1];
    }
    int addrA = (col + 16 * ((2 * g) & 3)) * 4;
    int addrB = (col + 16 * ((2 * g + 1) & 3)) * 4;
    int j0 = __builtin_amdgcn_ds_bpermute(addrA, w0);
    int j1 = __builtin_amdgcn_ds_bpermute(addrA, w1);
    int j2 = __builtin_amdgcn_ds_bpermute(addrB, w0);
    int j3 = __builtin_amdgcn_ds_bpermute(addrB, w1);
    bool lo2 = g < 2;
    FragU B;
    B.u[0] = lo2 ? j0 : 0;
    B.u[1] = lo2 ? j1 : 0;
    B.u[2] = lo2 ? j2 : 0;
    B.u[3] = lo2 ? j3 : 0;
    return B;
}

// gfrag prep (one wave; lane l). Permuted out-feature placement for layers 2,3:
// feature f -> tile (f>>2)&1, row 4*(f>>3)+(f&3); C/D layout then hands each lane
// exactly its next-layer B fragment (local rebuild, no cross-lane ops).
__device__ __forceinline__ void prep_frags_lane(int l,
        const float* w2, const float* w3, const float* w4, const float* w5,
        uint4* gfrag) {
    int rho = l & 15, g = l >> 4;
    int fbase = 8 * (rho >> 2) + (rho & 3);
    FragU F;
#pragma unroll
    for (int tt = 0; tt < 2; tt++)
#pragma unroll
        for (int kt = 0; kt < 2; kt++) {
#pragma unroll
            for (int j = 0; j < 4; j++) {
                int k = kt * 32 + g * 8 + 2 * j;
                F.h[j] = pkrtz(w2[k * 32 + fbase + 4 * tt],
                               w2[(k + 1) * 32 + fbase + 4 * tt]);
            }
            gfrag[(tt * 2 + kt) * 64 + l] = F.q;
        }
#pragma unroll
    for (int tt = 0; tt < 2; tt++) {
#pragma unroll
        for (int j = 0; j < 4; j++) {
            int k = g * 8 + 2 * j;
            F.h[j] = pkrtz(w3[k * 32 + fbase + 4 * tt],
                           w3[(k + 1) * 32 + fbase + 4 * tt]);
        }
        gfrag[(4 + tt) * 64 + l] = F.q;
    }
#pragma unroll
    for (int j = 0; j < 4; j++) {
        int k = g * 8 + 2 * j;
        F.h[j] = pkrtz(w4[k * 16 + rho], w4[(k + 1) * 16 + rho]);
    }
    gfrag[6 * 64 + l] = F.q;
#pragma unroll
    for (int j = 0; j < 4; j++) {
        int k = g * 8 + 2 * j;
        if (g < 2 && rho < 8)
            F.h[j] = pkrtz(w5[k * 8 + rho], w5[(k + 1) * 8 + rho]);
        else
            F.u[j] = 0;
    }
    gfrag[7 * 64 + l] = F.q;
}

// Two-phase edge-softmax-aggregate (128 threads). Leaves smf[64] = agg+bias.
#define AGG_BODY_V2(CUR, SLOTS, H, SS, SD, BIAS)                            \
    int deg = (CUR)[node]; if (deg > MAXD) deg = MAXD;                      \
    float sd = (SD)[node];                                                  \
    float myex = 0.f;                                                       \
    if (tid < deg) {                                                        \
        int s = (SLOTS)[node * MAXD + tid];                                 \
        smI[tid] = s;                                                       \
        float v = (SS)[s] + sd;                                             \
        v = v > 0.f ? v : 0.2f * v;                                         \
        myex = __expf(v);                                                   \
        smS[tid] = myex;                                                    \
    }                                                                       \
    float den = myex;                                                       \
    _Pragma("unroll")                                                       \
    for (int off = 1; off < 64; off <<= 1) den += __shfl_xor(den, off);     \
    if (t == 0) smD[wv] = den;                                              \
    __syncthreads();                                                        \
    float fullden = smD[0] + smD[1];                                        \
    int egrp = tid >> 3, q8 = tid & 7;                                      \
    float4 A0 = {0.f, 0.f, 0.f, 0.f}, A1 = {0.f, 0.f, 0.f, 0.f};            \
    _Pragma("unroll 2")                                                     \
    for (int i = egrp; i < deg; i += 16) {                                  \
        float ex = smS[i];                                                  \
        int s = smI[i];                                                     \
        const float4* hp = (const float4*)((H) + (size_t)s * 64 + q8 * 8);  \
        float4 h0 = hp[0], h1 = hp[1];                                      \
        A0.x = fmaf(ex, h0.x, A0.x); A0.y = fmaf(ex, h0.y, A0.y);           \
        A0.z = fmaf(ex, h0.z, A0.z); A0.w = fmaf(ex, h0.w, A0.w);           \
        A1.x = fmaf(ex, h1.x, A1.x); A1.y = fmaf(ex, h1.y, A1.y);           \
        A1.z = fmaf(ex, h1.z, A1.z); A1.w = fmaf(ex, h1.w, A1.w);           \
    }                                                                       \
    _Pragma("unroll")                                                       \
    for (int off = 8; off <= 32; off <<= 1) {                               \
        A0.x += __shfl_xor(A0.x, off); A0.y += __shfl_xor(A0.y, off);       \
        A0.z += __shfl_xor(A0.z, off); A0.w += __shfl_xor(A0.w, off);       \
        A1.x += __shfl_xor(A1.x, off); A1.y += __shfl_xor(A1.y, off);       \
        A1.z += __shfl_xor(A1.z, off); A1.w += __shfl_xor(A1.w, off);       \
    }                                                                       \
    if (t < 8) {                                                            \
        smA[wv][8 * t + 0] = A0.x; smA[wv][8 * t + 1] = A0.y;               \
        smA[wv][8 * t + 2] = A0.z; smA[wv][8 * t + 3] = A0.w;               \
        smA[wv][8 * t + 4] = A1.x; smA[wv][8 * t + 5] = A1.y;               \
        smA[wv][8 * t + 6] = A1.z; smA[wv][8 * t + 7] = A1.w;               \
    }                                                                       \
    __syncthreads();                                                        \
    if (wv == 0) {                                                          \
        float inv = 1.f / fullden;                                          \
        smf[t] = (smA[0][t] + smA[1][t]) * inv + (BIAS)[t];                 \
    }                                                                       \
    __syncthreads();

// MLP chain state + helpers.
struct MlpState {
    FragU A200, A201, A210, A211, A30, A31, A4f, A5f;
    float bias2[8], bias3[8], bias4[4], bias5[4], w6r[4];
    float b6v;
};
__device__ __forceinline__ void mlp_init(MlpState& S, int lane, const uint4* gfrag,
        const float* b2, const float* b3, const float* b4, const float* b5,
        const float* w6, const float* b6) {
    int g = lane >> 4;
    S.A200.q = gfrag[0 * 64 + lane];
    S.A201.q = gfrag[1 * 64 + lane];
    S.A210.q = gfrag[2 * 64 + lane];
    S.A211.q = gfrag[3 * 64 + lane];
    S.A30.q  = gfrag[4 * 64 + lane];
    S.A31.q  = gfrag[5 * 64 + lane];
    S.A4f.q  = gfrag[6 * 64 + lane];
    S.A5f.q  = gfrag[7 * 64 + lane];
#pragma unroll
    for (int i = 0; i < 8; i++) {
        S.bias2[i] = b2[8 * g + i];
        S.bias3[i] = b3[8 * g + i];
    }
#pragma unroll
    for (int r = 0; r < 4; r++) {
        S.bias4[r] = b4[g * 4 + r];
        S.bias5[r] = (g < 2) ? b5[g * 4 + r] : 0.f;
        S.w6r[r]   = (g < 2) ? w6[g * 4 + r] : 0.f;
    }
    S.b6v = b6[0];
}
__device__ __forceinline__ float mlp_chain(const MlpState& S, int col, int g,
        uint4 r0, uint4 r1, uint4 d0, uint4 d1) {
    const vf4 z = {0.f, 0.f, 0.f, 0.f};
    FragU B0, B1;
    B0.u[0] = addrelu2(r0.x, d0.x);
    B0.u[1] = addrelu2(r0.y, d0.y);
    B0.u[2] = addrelu2(r0.z, d0.z);
    B0.u[3] = addrelu2(r0.w, d0.w);
    B1.u[0] = addrelu2(r1.x, d1.x);
    B1.u[1] = addrelu2(r1.y, d1.y);
    B1.u[2] = addrelu2(r1.z, d1.z);
    B1.u[3] = addrelu2(r1.w, d1.w);
    vf4 acc0 = mfma16(S.A200, B0, z);
    acc0 = mfma16(S.A201, B1, acc0);
    vf4 acc1 = mfma16(S.A210, B0, z);
    acc1 = mfma16(S.A211, B1, acc1);
#pragma unroll
    for (int r = 0; r < 4; r++) {
        acc0[r] = fmaxf(acc0[r] + S.bias2[r], 0.f);
        acc1[r] = fmaxf(acc1[r] + S.bias2[4 + r], 0.f);
    }
    FragU Bx;
    Bx.h[0] = pkrtz(acc0[0], acc0[1]);
    Bx.h[1] = pkrtz(acc0[2], acc0[3]);
    Bx.h[2] = pkrtz(acc1[0], acc1[1]);
    Bx.h[3] = pkrtz(acc1[2], acc1[3]);
    acc0 = mfma16(S.A30, Bx, z);
    acc1 = mfma16(S.A31, Bx, z);
#pragma unroll
    for (int r = 0; r < 4; r++) {
        acc0[r] = fmaxf(acc0[r] + S.bias3[r], 0.f);
        acc1[r] = fmaxf(acc1[r] + S.bias3[4 + r], 0.f);
    }
    Bx.h[0] = pkrtz(acc0[0], acc0[1]);
    Bx.h[1] = pkrtz(acc0[2], acc0[3]);
    Bx.h[2] = pkrtz(acc1[0], acc1[1]);
    Bx.h[3] = pkrtz(acc1[2], acc1[3]);
    vf4 a4 = mfma16(S.A4f, Bx, z);
#pragma unroll
    for (int r = 0; r < 4; r++) a4[r] = fmaxf(a4[r] + S.bias4[r], 0.f);
    Bx = trans16(a4, col, g);
    vf4 a5 = mfma16(S.A5f, Bx, z);
    float part = 0.f;
#pragma unroll
    for (int r = 0; r < 4; r++)
        part = fmaf(fmaxf(a5[r] + S.bias5[r], 0.f), S.w6r[r], part);
    part += __shfl_xor(part, 16);
    return 1.f / (1.f + __expf(-(part + S.b6v)));
}
__device__ __forceinline__ void mlp_loop(const MlpState& S, int wid, int nwaves,
        int lane, const _Float16* u1h, const _Float16* u2h, const int* coo,
        float* out) {
    const int col = lane & 15, g = lane >> 4;
    int tile = wid;
    uint4 r0, r1, d0, d1;
    if (tile < NTILE) {
        int pp = tile * 16 + col;
        int2 rd = ((const int2*)coo)[pp];
        const uint4* pr = (const uint4*)(u1h + (size_t)rd.x * 64);
        const uint4* pd = (const uint4*)(u2h + (size_t)rd.y * 64);
        r0 = pr[g]; r1 = pr[4 + g]; d0 = pd[g]; d1 = pd[4 + g];
    }
    while (tile < NTILE) {
        int next = tile + nwaves;
        uint4 nr0, nr1, nd0, nd1;
        if (next < NTILE) {
            int pp = next * 16 + col;
            int2 rd = ((const int2*)coo)[pp];
            const uint4* pr = (const uint4*)(u1h + (size_t)rd.x * 64);
            const uint4* pd = (const uint4*)(u2h + (size_t)rd.y * 64);
            nr0 = pr[g]; nr1 = pr[4 + g]; nd0 = pd[g]; nd1 = pd[4 + g];
        }
        float sig = mlp_chain(S, col, g, r0, r1, d0, d1);
        if (g == 0) out[tile * 16 + col] = sig;
        tile = next;
        r0 = nr0; r1 = nr1; d0 = nd0; d1 = nd1;
    }
}

// ================= 5-kernel pipeline (R15-proven; ushort slots) =============
__global__ void setup_kernel(int* __restrict__ cur,
                             const float* __restrict__ w2, const float* __restrict__ w3,
                             const float* __restrict__ w4, const float* __restrict__ w5,
                             uint4* __restrict__ gfrag) {
    int i = blockIdx.x * blockDim.x + threadIdx.x;
    if (i < NNODE) cur[i] = 0;
    if (blockIdx.x == 0 && threadIdx.x < 64)
        prep_frags_lane(threadIdx.x, w2, w3, w4, w5, gfrag);
}

__global__ __launch_bounds__(256) void fill_proj_kernel(
    const int* __restrict__ adj, int* __restrict__ cur, unsigned short* __restrict__ slots,
    const float* __restrict__ x, const float* __restrict__ W,
    const float* __restrict__ a_s, const float* __restrict__ a_d,
    float* __restrict__ h, float* __restrict__ ssrc, float* __restrict__ sdst) {
    int b = blockIdx.x;
    if (b < FILLB) {
        int k = b * 256 + threadIdx.x;
        if (k >= NET) return;
        int src, dst;
        if (k < NE) { src = adj[k]; dst = adj[NE + k]; }
        else        { src = k - NE; dst = k - NE; }
        int pos = atomicAdd(&cur[dst], 1);
        if ((unsigned)pos < MAXD) slots[dst * MAXD + pos] = (unsigned short)src;
        return;
    }
    __shared__ float xr[16][NFDIM];
    int pb = b - FILLB;
    int wv = threadIdx.x >> 6, t = threadIdx.x & 63;
    int nb = pb * 16 + wv * 4;
    for (int idx = t; idx < 4 * NFDIM; idx += 64)
        xr[wv * 4 + idx / NFDIM][idx % NFDIM] = x[(size_t)nb * NFDIM + idx];
    __syncthreads();
    float a0 = 0.f, a1 = 0.f, a2 = 0.f, a3 = 0.f;
#pragma unroll 8
    for (int k = 0; k < NFDIM; k++) {
        float wvv = W[k * RDIM + t];
        a0 = fmaf(xr[wv * 4 + 0][k], wvv, a0);
        a1 = fmaf(xr[wv * 4 + 1][k], wvv, a1);
        a2 = fmaf(xr[wv * 4 + 2][k], wvv, a2);
        a3 = fmaf(xr[wv * 4 + 3][k], wvv, a3);
    }
    h[(size_t)(nb + 0) * RDIM + t] = a0;
    h[(size_t)(nb + 1) * RDIM + t] = a1;
    h[(size_t)(nb + 2) * RDIM + t] = a2;
    h[(size_t)(nb + 3) * RDIM + t] = a3;
    float asv = a_s[t], adv = a_d[t];
    float acc[4] = {a0, a1, a2, a3};
#pragma unroll
    for (int i = 0; i < 4; i++) {
        float vs = acc[i] * asv;
        float vd = acc[i] * adv;
#pragma unroll
        for (int off = 32; off; off >>= 1) {
            vs += __shfl_down(vs, off);
            vd += __shfl_down(vd, off);
        }
        if (t == 0) { ssrc[nb + i] = vs; sdst[nb + i] = vd; }
    }
}

__global__ __launch_bounds__(128) void agg_proj_kernel(
    const float* __restrict__ h, const float* __restrict__ ssrc, const float* __restrict__ sdst,
    const int* __restrict__ cur, const unsigned short* __restrict__ slots,
    const float* __restrict__ bias, const float* __restrict__ W,
    const float* __restrict__ a_s, const float* __restrict__ a_d,
    float* __restrict__ h2, float* __restrict__ ssrc2, float* __restrict__ sdst2) {
    __shared__ float smS[MAXD];
    __shared__ int   smI[MAXD];
    __shared__ float smA[2][64];
    __shared__ float smD[2];
    __shared__ float smf[64];
    __shared__ float smP[64];
    int node = blockIdx.x;
    int tid = threadIdx.x;
    int wv = tid >> 6, t = tid & 63;
    AGG_BODY_V2(cur, slots, h, ssrc, sdst, bias)
    float part = 0.f;
    int k0 = wv * 32;
#pragma unroll 8
    for (int k = 0; k < 32; k++) part = fmaf(smf[k0 + k], W[(k0 + k) * 64 + t], part);
    if (wv == 1) smP[t] = part;
    __syncthreads();
    if (wv == 0) {
        float hv = part + smP[t];
        h2[(size_t)node * 64 + t] = hv;
        float vs = hv * a_s[t];
        float vd = hv * a_d[t];
#pragma unroll
        for (int off = 32; off; off >>= 1) {
            vs += __shfl_down(vs, off);
            vd += __shfl_down(vd, off);
        }
        if (t == 0) { ssrc2[node] = vs; sdst2[node] = vd; }
    }
}

__global__ __launch_bounds__(128) void agg_pre_kernel(
    const float* __restrict__ h, const float* __restrict__ ssrc, const float* __restrict__ sdst,
    const int* __restrict__ cur, const unsigned short* __restrict__ slots,
    const float* __restrict__ bias,
    const float* __restrict__ w1, const float* __restrict__ b1,
    _Float16* __restrict__ u1h, _Float16* __restrict__ u2h) {
    __shared__ float smS[MAXD];
    __shared__ int   smI[MAXD];
    __shared__ float smA[2][64];
    __shared__ float smD[2];
    __shared__ float smf[64];
    __shared__ float smP[64];
    int node = blockIdx.x;
    int tid = threadIdx.x;
    int wv = tid >> 6, t = tid & 63;
    AGG_BODY_V2(cur, slots, h, ssrc, sdst, bias)
    bool rna = node < N_RNA;
    const float* w = rna ? w1 : (w1 + 64 * 64);
    float part = (wv == 0 && rna) ? b1[t] : 0.f;
    int k0 = wv * 32;
#pragma unroll 8
    for (int k = 0; k < 32; k++) part = fmaf(smf[k0 + k], w[(k0 + k) * 64 + t], part);
    if (wv == 1) smP[t] = part;
    __syncthreads();
    if (wv == 0) {
        float uk = part + smP[t];
        _Float16* dst = rna ? (u1h + (size_t)node * 64) : (u2h + (size_t)(node - N_RNA) * 64);
        dst[t] = (_Float16)uk;
    }
}

__global__ __launch_bounds__(256) void mlp_mfma_kernel(
    const _Float16* __restrict__ u1h, const _Float16* __restrict__ u2h,
    const int* __restrict__ coo, const uint4* __restrict__ gfrag,
    const float* __restrict__ b2, const float* __restrict__ b3,
    const float* __restrict__ b4, const float* __restrict__ b5,
    const float* __restrict__ w6, const float* __restrict__ b6,
    float* __restrict__ out) {
    int tid = threadIdx.x;
    const int lane = tid & 63;
    MlpState S;
    mlp_init(S, lane, gfrag, b2, b3, b4, b5, w6, b6);
    mlp_loop(S, blockIdx.x * 4 + (tid >> 6), gridDim.x * 4, lane, u1h, u2h, coo, out);
}

// ---------------- launch ----------------
extern "C" void kernel_launch(void* const* d_in, const int* in_sizes, int n_in,
                              void* d_out, int out_size, void* d_ws, size_t ws_size,
                              hipStream_t stream) {
    const float* x    = (const float*)d_in[0];
    const int*   adj  = (const int*)d_in[1];
    const int*   coo  = (const int*)d_in[2];
    const float* gw0  = (const float*)d_in[3];
    const float* gas0 = (const float*)d_in[4];
    const float* gad0 = (const float*)d_in[5];
    const float* gb0  = (const float*)d_in[6];
    const float* gw1  = (const float*)d_in[7];
    const float* gas1 = (const float*)d_in[8];
    const float* gad1 = (const float*)d_in[9];
    const float* gb1  = (const float*)d_in[10];

    char* ws = (char*)d_ws;
    size_t o = 0;
    auto take = [&](size_t bytes) -> void* {
        void* ptr = ws + o;
        o = (o + bytes + 255) & ~(size_t)255;
        return ptr;
    };
    float*          hP    = (float*)take((size_t)NNODE * RDIM * 4);
    float*          hP2   = (float*)take((size_t)NNODE * RDIM * 4);
    _Float16*       u1h   = (_Float16*)take((size_t)N_RNA * 64 * 2);
    _Float16*       u2h   = (_Float16*)take((size_t)N_DIS * 64 * 2);
    uint4*          gfrag = (uint4*)take((size_t)8 * 64 * 16);
    float*          ssrc  = (float*)take((size_t)NNODE * 4);
    float*          sdst  = (float*)take((size_t)NNODE * 4);
    float*          ssrc2 = (float*)take((size_t)NNODE * 4);
    float*          sdst2 = (float*)take((size_t)NNODE * 4);
    int*            cur   = (int*)take((size_t)NNODE * 4);
    unsigned short* slots = (unsigned short*)take((size_t)NNODE * MAXD * 2);

    // 1: zero slot counters + prep MLP weight fragments
    setup_kernel<<<(NNODE + 255) / 256, 256, 0, stream>>>(
        cur, (const float*)d_in[13], (const float*)d_in[15],
        (const float*)d_in[17], (const float*)d_in[19], gfrag);
    // 2: merged edge fill + layer-1 projection
    fill_proj_kernel<<<FILLB + PROJB, 256, 0, stream>>>(
        adj, cur, slots, x, gw0, gas0, gad0, hP, ssrc, sdst);
    // 3: layer-1 aggregate + fused layer-2 projection + scores
    agg_proj_kernel<<<NNODE, 128, 0, stream>>>(
        hP, ssrc, sdst, cur, slots, gb0, gw1, gas1, gad1, hP2, ssrc2, sdst2);
    // 4: layer-2 aggregate + fused MLP layer-1 precompute (f16 u-rows)
    agg_pre_kernel<<<N_RNA + N_DIS, 128, 0, stream>>>(
        hP2, ssrc2, sdst2, cur, slots, gb1,
        (const float*)d_in[11], (const float*)d_in[12], u1h, u2h);
    // 5: pairwise MLP (load-ahead-1 pipeline)
    mlp_mfma_kernel<<<2048, 256, 0, stream>>>(
        u1h, u2h, coo, gfrag,
        (const float*)d_in[14], (const float*)d_in[16],
        (const float*)d_in[18], (const float*)d_in[20],
        (const float*)d_in[21], (const float*)d_in[22],
        (float*)d_out);
}